// Round 5
// baseline (73.066 us; speedup 1.0000x reference)
//
#include <hip/hip_runtime.h>
#include <stdint.h>

#define B_   32
#define L_   8192
#define D_   128
#define KTOP 512
#define NBINS 4096
#define CAP  1024   // candidate capacity (sel[] size)

typedef float v4f __attribute__((ext_vector_type(4)));

// ---------------- Threefry-2x32, key = (0, 42), 20 rounds ----------------
// jax.random.key(42) -> key pair (0, 42); threefry_partitionable 32-bit path:
// bits(p) = x0 ^ x1 of block (hi=0, lo=p).
__device__ __forceinline__ uint32_t rotl32(uint32_t x, int d) {
    return (x << d) | (x >> (32 - d));
}

__device__ __forceinline__ uint32_t threefry_bits(uint32_t p) {
    const uint32_t k0 = 0u, k1 = 42u;
    const uint32_t k2 = 0x1BD11BDAu ^ k0 ^ k1;
    uint32_t x0 = 0u + k0;   // c0 + ks0
    uint32_t x1 = p + k1;    // c1 + ks1
#define TF_R(r) { x0 += x1; x1 = rotl32(x1, r); x1 ^= x0; }
    TF_R(13) TF_R(15) TF_R(26) TF_R(6)   x0 += k1; x1 += k2 + 1u;
    TF_R(17) TF_R(29) TF_R(16) TF_R(24)  x0 += k2; x1 += k0 + 2u;
    TF_R(13) TF_R(15) TF_R(26) TF_R(6)   x0 += k0; x1 += k1 + 3u;
    TF_R(17) TF_R(29) TF_R(16) TF_R(24)  x0 += k1; x1 += k2 + 4u;
    TF_R(13) TF_R(15) TF_R(26) TF_R(6)   x0 += k2; x1 += k0 + 5u;
#undef TF_R
    return x0 ^ x1;
}

// One block per batch row. Packed keys -> ONE 12-bit histogram + suffix scan
// (rare refine loop for ties). Rank of each candidate = above[bin] + tiny
// intra-bin scan (bins hold ~2 elems) -- no O(nc^2) loop, no bitonic sort.
__global__ __launch_bounds__(1024) void select_kernel(
        const float* __restrict__ probs, const float* __restrict__ mask,
        float* __restrict__ out_ind, uint32_t* __restrict__ keepw) {
    const int b    = blockIdx.x;
    const int tid  = threadIdx.x;
    const int lane = tid & 63;
    const int wid  = tid >> 6;

    __shared__ uint32_t hist[NBINS];    // 16 KB; reused as per-bin cursor
    __shared__ uint32_t above[NBINS];   // 16 KB; exclusive suffix counts
    __shared__ uint64_t sel[CAP];       // 8 KB; candidates grouped by bin
    __shared__ uint32_t wtot[16];
    __shared__ uint32_t s_bin, s_above, s_candv;

    // zero this row's keep bitmap (256 words = 8192 bits)
    if (tid < 256) keepw[b * 256 + tid] = 0u;

    // ---- packed sort keys: (monotone(y) << 16) | (8191 - l) ----
    uint64_t K[8];
#pragma unroll
    for (int j = 0; j < 8; ++j) {
        const int l = j * 1024 + tid;
        const int p = b * L_ + l;
        const uint32_t bits = threefry_bits((uint32_t)p);
        const float U = __uint_as_float((bits >> 9) | 0x3F800000u) - 1.0f;
        const float g = -logf(-logf(U + 1e-20f) + 1e-20f);
        const float y = probs[p] / 0.1f + g + mask[p] * (-10000.0f);
        const uint32_t u = __float_as_uint(y);
        const uint32_t mono = u ^ ((u & 0x80000000u) ? 0xFFFFFFFFu : 0x80000000u);
        K[j] = ((uint64_t)mono << 16) | (uint32_t)(8191 - l);
    }

    // ---- threshold search: 12-bit digits; level 0 also records above[] ----
    uint64_t prefix = 0;
    uint32_t needed = KTOP;
    uint64_t thrlo  = 0;
    for (int level = 0; level < 4; ++level) {
        const int shift = 36 - level * 12;
        for (int i = tid; i < NBINS; i += 1024) hist[i] = 0u;
        __syncthreads();
#pragma unroll
        for (int j = 0; j < 8; ++j) {
            const bool match = (level == 0) || ((K[j] >> (shift + 12)) == prefix);
            if (match) atomicAdd(&hist[(uint32_t)(K[j] >> shift) & (NBINS - 1u)], 1u);
        }
        __syncthreads();

        // suffix scan: thread t owns bins 4t..4t+3
        const uint32_t h0 = hist[4 * tid + 0];
        const uint32_t h1 = hist[4 * tid + 1];
        const uint32_t h2 = hist[4 * tid + 2];
        const uint32_t h3 = hist[4 * tid + 3];
        const uint32_t ls = h0 + h1 + h2 + h3;
        uint32_t s = ls;
#pragma unroll
        for (int off = 1; off < 64; off <<= 1) {
            const uint32_t v = __shfl_down(s, off);
            if (lane + off < 64) s += v;
        }
        if (lane == 0) wtot[wid] = s;      // whole-wave sum
        __syncthreads();
        uint32_t after_waves = 0;
        for (int w = wid + 1; w < 16; ++w) after_waves += wtot[w];
        const uint32_t base = after_waves + (s - ls);  // sum of bins after my 4
        const uint32_t s3 = h3 + base;
        const uint32_t s2 = h2 + s3;
        const uint32_t s1 = h1 + s2;
        const uint32_t s0 = h0 + s1;
        if (level == 0) {   // exclusive suffix counts for rank bases
            above[4 * tid + 0] = s1;
            above[4 * tid + 1] = s2;
            above[4 * tid + 2] = s3;
            above[4 * tid + 3] = base;
        }
        if (s0 >= needed && s1 < needed)  { s_bin = 4u*tid+0u; s_above = s1;  s_candv = s0; }
        if (s1 >= needed && s2 < needed)  { s_bin = 4u*tid+1u; s_above = s2;  s_candv = s1; }
        if (s2 >= needed && s3 < needed)  { s_bin = 4u*tid+2u; s_above = s3;  s_candv = s2; }
        if (s3 >= needed && base < needed){ s_bin = 4u*tid+3u; s_above = base;s_candv = s3; }
        __syncthreads();

        const uint32_t T = s_bin;
        thrlo = ((prefix << 12) | T) << shift;          // conservative threshold
        const uint32_t G = s_candv + (KTOP - needed);   // global candidate count
        if (G <= CAP) break;                            // ~always at level 0
        prefix = (prefix << 12) | T;
        needed -= s_above;
        __syncthreads();
    }

    // ---- place candidates grouped by level-0 bin: slot = above[bin]+cursor ----
    for (int i = tid; i < NBINS; i += 1024) hist[i] = 0u;   // hist -> cursor
    __syncthreads();
#pragma unroll
    for (int j = 0; j < 8; ++j) {
        if (K[j] >= thrlo) {
            const uint32_t bin = (uint32_t)(K[j] >> 36);
            const uint32_t slot = above[bin] + atomicAdd(&hist[bin], 1u);
            sel[slot] = K[j];
        }
    }
    __syncthreads();

    // ---- exact rank = above[bin] + #{same-bin candidates with larger key} ----
#pragma unroll
    for (int j = 0; j < 8; ++j) {
        if (K[j] >= thrlo) {
            const uint64_t mine = K[j];
            const uint32_t bin  = (uint32_t)(mine >> 36);
            const uint32_t base2 = above[bin];
            const uint32_t cnt  = hist[bin];   // final cursor = candidates in bin
            uint32_t r = base2;
            for (uint32_t k = 0; k < cnt; ++k) r += (uint32_t)(sel[base2 + k] > mine);
            if (r < KTOP) {
                const uint32_t idx = 8191u - (uint32_t)(mine & 0xFFFFu);
                out_ind[b * KTOP + r] = (float)idx;
                atomicOr(&keepw[b * 256 + (idx >> 5)], 1u << (idx & 31u));
            }
        }
    }
}

// Fused scatter: full [B, L, D] output, reps row if kept else zeros.
// 4-way ILP: each thread owns 4 independent float4s 32 MB apart.
__global__ __launch_bounds__(256) void scatter_kernel(
        const float* __restrict__ reps, const uint32_t* __restrict__ keepw,
        float* __restrict__ out) {
    const v4f* r4 = (const v4f*)reps;
    v4f* o4 = (v4f*)out;
    const uint32_t STR = (B_ * L_ * D_ / 4) / 4;   // 2,097,152 float4
    const uint32_t t = blockIdx.x * 256u + threadIdx.x;
    const uint32_t i0 = t, i1 = t + STR, i2 = t + 2 * STR, i3 = t + 3 * STR;
    const uint32_t w0 = keepw[i0 >> 10];
    const uint32_t w1 = keepw[i1 >> 10];
    const uint32_t w2 = keepw[i2 >> 10];
    const uint32_t w3 = keepw[i3 >> 10];
    const v4f z = {0.f, 0.f, 0.f, 0.f};
    v4f v0 = z, v1 = z, v2 = z, v3 = z;
    if ((w0 >> ((i0 >> 5) & 31u)) & 1u) v0 = r4[i0];
    if ((w1 >> ((i1 >> 5) & 31u)) & 1u) v1 = r4[i1];
    if ((w2 >> ((i2 >> 5) & 31u)) & 1u) v2 = r4[i2];
    if ((w3 >> ((i3 >> 5) & 31u)) & 1u) v3 = r4[i3];
    o4[i0] = v0;
    o4[i1] = v1;
    o4[i2] = v2;
    o4[i3] = v3;
}

extern "C" void kernel_launch(void* const* d_in, const int* in_sizes, int n_in,
                              void* d_out, int out_size, void* d_ws, size_t ws_size,
                              hipStream_t stream) {
    const float* reps  = (const float*)d_in[0];
    const float* probs = (const float*)d_in[1];
    const float* mask  = (const float*)d_in[2];
    float* out     = (float*)d_out;
    float* out_ind = out + (size_t)B_ * L_ * D_;
    uint32_t* keepw = (uint32_t*)d_ws;   // B_*L_/32 = 8192 words (32 KB)

    hipLaunchKernelGGL(select_kernel, dim3(B_), dim3(1024), 0, stream,
                       probs, mask, out_ind, keepw);
    const uint32_t nthread = (B_ * L_ * D_ / 4) / 4;   // 2,097,152 threads
    hipLaunchKernelGGL(scatter_kernel, dim3(nthread / 256), dim3(256), 0, stream,
                       reps, keepw, out);
}

// Round 6
// 48.760 us; speedup vs baseline: 1.4985x; 1.4985x over previous
//
#include <hip/hip_runtime.h>
#include <stdint.h>

#define B_   32
#define L_   8192
#define D_   128
#define KTOP 512
#define NBINS 4096
#define CAP  1024   // candidate capacity (sel[] size)

typedef float v4f __attribute__((ext_vector_type(4)));

// ---------------- Threefry-2x32, key = (0, 42), 20 rounds ----------------
// jax.random.key(42) -> key pair (0, 42); threefry_partitionable 32-bit path:
// bits(p) = x0 ^ x1 of block (hi=0, lo=p).
__device__ __forceinline__ uint32_t rotl32(uint32_t x, int d) {
    return (x << d) | (x >> (32 - d));
}

__device__ __forceinline__ uint32_t threefry_bits(uint32_t p) {
    const uint32_t k0 = 0u, k1 = 42u;
    const uint32_t k2 = 0x1BD11BDAu ^ k0 ^ k1;
    uint32_t x0 = 0u + k0;   // c0 + ks0
    uint32_t x1 = p + k1;    // c1 + ks1
#define TF_R(r) { x0 += x1; x1 = rotl32(x1, r); x1 ^= x0; }
    TF_R(13) TF_R(15) TF_R(26) TF_R(6)   x0 += k1; x1 += k2 + 1u;
    TF_R(17) TF_R(29) TF_R(16) TF_R(24)  x0 += k2; x1 += k0 + 2u;
    TF_R(13) TF_R(15) TF_R(26) TF_R(6)   x0 += k0; x1 += k1 + 3u;
    TF_R(17) TF_R(29) TF_R(16) TF_R(24)  x0 += k1; x1 += k2 + 4u;
    TF_R(13) TF_R(15) TF_R(26) TF_R(6)   x0 += k2; x1 += k0 + 5u;
#undef TF_R
    return x0 ^ x1;
}

// One block per batch row (round-2-validated structure). Packed keys -> one
// 12-bit histogram + suffix scan (refine loop for pathological ties) ->
// compact candidates -> rank-by-counting. Writes indices as float (output)
// and as int (for copy_kernel).
__global__ __launch_bounds__(1024) void select_kernel(
        const float* __restrict__ probs, const float* __restrict__ mask,
        float* __restrict__ out_ind, int* __restrict__ ind_i32) {
    const int b    = blockIdx.x;
    const int tid  = threadIdx.x;
    const int lane = tid & 63;
    const int wid  = tid >> 6;

    __shared__ uint32_t hist[NBINS];       // 16 KB
    __shared__ uint64_t sel[CAP];          // 8 KB
    __shared__ uint32_t wtot[16];
    __shared__ uint32_t s_bin, s_above, s_candv, s_cnt;

    // ---- packed sort keys: (monotone(y) << 16) | (8191 - l) ----
    uint64_t K[8];
#pragma unroll
    for (int j = 0; j < 8; ++j) {
        const int l = j * 1024 + tid;
        const int p = b * L_ + l;
        const uint32_t bits = threefry_bits((uint32_t)p);
        const float U = __uint_as_float((bits >> 9) | 0x3F800000u) - 1.0f;
        const float g = -logf(-logf(U + 1e-20f) + 1e-20f);
        const float y = probs[p] / 0.1f + g + mask[p] * (-10000.0f);
        const uint32_t u = __float_as_uint(y);
        const uint32_t mono = u ^ ((u & 0x80000000u) ? 0xFFFFFFFFu : 0x80000000u);
        K[j] = ((uint64_t)mono << 16) | (uint32_t)(8191 - l);
    }

    // ---- threshold search: 12-bit digits, usually exits after level 0 ----
    uint64_t prefix = 0;
    uint32_t needed = KTOP;
    uint64_t thrlo  = 0;
    for (int level = 0; level < 4; ++level) {
        const int shift = 36 - level * 12;
        for (int i = tid; i < NBINS; i += 1024) hist[i] = 0u;
        __syncthreads();
#pragma unroll
        for (int j = 0; j < 8; ++j) {
            const bool match = (level == 0) || ((K[j] >> (shift + 12)) == prefix);
            if (match) atomicAdd(&hist[(uint32_t)(K[j] >> shift) & (NBINS - 1u)], 1u);
        }
        __syncthreads();

        // suffix scan: thread t owns bins 4t..4t+3
        const uint32_t h0 = hist[4 * tid + 0];
        const uint32_t h1 = hist[4 * tid + 1];
        const uint32_t h2 = hist[4 * tid + 2];
        const uint32_t h3 = hist[4 * tid + 3];
        const uint32_t ls = h0 + h1 + h2 + h3;
        uint32_t s = ls;
#pragma unroll
        for (int off = 1; off < 64; off <<= 1) {
            const uint32_t v = __shfl_down(s, off);
            if (lane + off < 64) s += v;
        }
        if (lane == 0) wtot[wid] = s;      // whole-wave sum
        __syncthreads();
        uint32_t after_waves = 0;
        for (int w = wid + 1; w < 16; ++w) after_waves += wtot[w];
        const uint32_t base = after_waves + (s - ls);  // sum of bins after my 4
        const uint32_t s3 = h3 + base;
        const uint32_t s2 = h2 + s3;
        const uint32_t s1 = h1 + s2;
        const uint32_t s0 = h0 + s1;
        if (s0 >= needed && s1 < needed)  { s_bin = 4u*tid+0u; s_above = s1;  s_candv = s0; }
        if (s1 >= needed && s2 < needed)  { s_bin = 4u*tid+1u; s_above = s2;  s_candv = s1; }
        if (s2 >= needed && s3 < needed)  { s_bin = 4u*tid+2u; s_above = s3;  s_candv = s2; }
        if (s3 >= needed && base < needed){ s_bin = 4u*tid+3u; s_above = base;s_candv = s3; }
        __syncthreads();

        const uint32_t T = s_bin;
        thrlo = ((prefix << 12) | T) << shift;          // conservative threshold
        const uint32_t G = s_candv + (KTOP - needed);   // global candidate count
        if (G <= CAP) break;                            // ~always at level 0
        prefix = (prefix << 12) | T;
        needed -= s_above;
        __syncthreads();
    }

    // ---- compact candidates (keys >= thrlo) ----
    if (tid == 0) s_cnt = 0u;
    __syncthreads();
#pragma unroll
    for (int j = 0; j < 8; ++j) {
        if (K[j] >= thrlo) {
            const uint32_t pos = atomicAdd(&s_cnt, 1u);
            sel[pos] = K[j];
        }
    }
    __syncthreads();
    const uint32_t nc = s_cnt;

    // ---- rank-position: r = #{candidates with larger key}; write r < KTOP ----
    if (tid < (int)nc) {
        const uint64_t mine = sel[tid];
        uint32_t r = 0;
        uint32_t i = 0;
        for (; i + 4 <= nc; i += 4) {
            r += (uint32_t)(sel[i]     > mine);
            r += (uint32_t)(sel[i + 1] > mine);
            r += (uint32_t)(sel[i + 2] > mine);
            r += (uint32_t)(sel[i + 3] > mine);
        }
        for (; i < nc; ++i) r += (uint32_t)(sel[i] > mine);
        if (r < KTOP) {
            const uint32_t idx = 8191u - (uint32_t)(mine & 0xFFFFu);
            out_ind[b * KTOP + r] = (float)idx;
            ind_i32[b * KTOP + r] = (int)idx;
        }
    }
}

// Pure streaming zero, rocclr-fill pattern: each block owns a CONTIGUOUS
// 1024-float4 (16 KB) chunk; thread t writes t, t+256, t+512, t+768.
// Every wave-store is 1 KB contiguous; no long-range strides.
__global__ __launch_bounds__(256) void zero_kernel(float* __restrict__ out) {
    v4f* o = (v4f*)out;
    const uint32_t base = blockIdx.x * 1024u + threadIdx.x;
    const v4f z = {0.f, 0.f, 0.f, 0.f};
    o[base]        = z;
    o[base + 256]  = z;
    o[base + 512]  = z;
    o[base + 768]  = z;
}

// Copies the 512 selected rows per batch from reps over the zeros.
// Block = 256 threads = 8 rows (32 lanes/row, one v4f each).
__global__ __launch_bounds__(256) void copy_kernel(
        const float* __restrict__ reps, const int* __restrict__ ind_i32,
        float* __restrict__ out) {
    const int b     = blockIdx.x >> 6;          // 64 blocks per batch
    const int group = blockIdx.x & 63;
    const int r     = group * 8 + (threadIdx.x >> 5);
    const int t     = threadIdx.x & 31;
    const int idx   = ind_i32[b * KTOP + r];
    const size_t off = ((size_t)b * L_ + idx) * D_ + (size_t)t * 4;
    *(v4f*)(out + off) = *(const v4f*)(reps + off);
}

extern "C" void kernel_launch(void* const* d_in, const int* in_sizes, int n_in,
                              void* d_out, int out_size, void* d_ws, size_t ws_size,
                              hipStream_t stream) {
    const float* reps  = (const float*)d_in[0];
    const float* probs = (const float*)d_in[1];
    const float* mask  = (const float*)d_in[2];
    float* out     = (float*)d_out;
    float* out_ind = out + (size_t)B_ * L_ * D_;
    int* ind_i32   = (int*)d_ws;   // B_*KTOP ints = 64 KB

    hipLaunchKernelGGL(zero_kernel, dim3((B_ * L_ * D_ / 4) / 1024), dim3(256),
                       0, stream, out);
    hipLaunchKernelGGL(select_kernel, dim3(B_), dim3(1024), 0, stream,
                       probs, mask, out_ind, ind_i32);
    hipLaunchKernelGGL(copy_kernel, dim3(B_ * (KTOP / 8)), dim3(256), 0, stream,
                       reps, ind_i32, out);
}

// Round 7
// 44.060 us; speedup vs baseline: 1.6583x; 1.1067x over previous
//
#include <hip/hip_runtime.h>
#include <stdint.h>

#define B_   32
#define L_   8192
#define D_   128
#define KTOP 512
#define NBINS 4096
#define CAP  1024   // candidate capacity (sel[] size)

typedef float v4f __attribute__((ext_vector_type(4)));

// ---------------- Threefry-2x32, key = (0, 42), 20 rounds ----------------
// jax.random.key(42) -> key pair (0, 42); threefry_partitionable 32-bit path:
// bits(p) = x0 ^ x1 of block (hi=0, lo=p).
__device__ __forceinline__ uint32_t rotl32(uint32_t x, int d) {
    return (x << d) | (x >> (32 - d));
}

__device__ __forceinline__ uint32_t threefry_bits(uint32_t p) {
    const uint32_t k0 = 0u, k1 = 42u;
    const uint32_t k2 = 0x1BD11BDAu ^ k0 ^ k1;
    uint32_t x0 = 0u + k0;   // c0 + ks0
    uint32_t x1 = p + k1;    // c1 + ks1
#define TF_R(r) { x0 += x1; x1 = rotl32(x1, r); x1 ^= x0; }
    TF_R(13) TF_R(15) TF_R(26) TF_R(6)   x0 += k1; x1 += k2 + 1u;
    TF_R(17) TF_R(29) TF_R(16) TF_R(24)  x0 += k2; x1 += k0 + 2u;
    TF_R(13) TF_R(15) TF_R(26) TF_R(6)   x0 += k0; x1 += k1 + 3u;
    TF_R(17) TF_R(29) TF_R(16) TF_R(24)  x0 += k1; x1 += k2 + 4u;
    TF_R(13) TF_R(15) TF_R(26) TF_R(6)   x0 += k2; x1 += k0 + 5u;
#undef TF_R
    return x0 ^ x1;
}

// Fused: every block streams 16 KB of zeros into out (validated R6 pattern);
// the first 1024 blocks ALSO compute 256 packed sort keys each (full-chip
// keygen, VALU rides under the store stream) and write them to ws.
__global__ __launch_bounds__(256) void zero_keys_kernel(
        const float* __restrict__ probs, const float* __restrict__ mask,
        float* __restrict__ out, uint64_t* __restrict__ keys) {
    const uint32_t blk = blockIdx.x;
    v4f* o = (v4f*)out;
    const uint32_t base = blk * 1024u + threadIdx.x;
    const v4f z = {0.f, 0.f, 0.f, 0.f};
    o[base]       = z;
    o[base + 256] = z;
    o[base + 512] = z;
    o[base + 768] = z;

    if (blk < 1024u) {
        const uint32_t e = blk * 256u + threadIdx.x;   // flat index, 0..262143
        const uint32_t l = e & (L_ - 1u);
        const uint32_t bits = threefry_bits(e);
        const float U = __uint_as_float((bits >> 9) | 0x3F800000u) - 1.0f;
        const float g = -logf(-logf(U + 1e-20f) + 1e-20f);
        const float y = probs[e] / 0.1f + g + mask[e] * (-10000.0f);
        const uint32_t u = __float_as_uint(y);
        const uint32_t mono = u ^ ((u & 0x80000000u) ? 0xFFFFFFFFu : 0x80000000u);
        keys[e] = ((uint64_t)mono << 16) | (uint32_t)(8191u - l);
    }
}

// One block per batch row (R2-validated structure), keys preloaded from ws.
// 12-bit histogram + suffix scan (refine loop for pathological ties) ->
// compact -> rank-by-counting -> write indices (float out, int for copy).
__global__ __launch_bounds__(1024) void select_kernel(
        const uint64_t* __restrict__ keys,
        float* __restrict__ out_ind, int* __restrict__ ind_i32) {
    const int b    = blockIdx.x;
    const int tid  = threadIdx.x;
    const int lane = tid & 63;
    const int wid  = tid >> 6;

    __shared__ uint32_t hist[NBINS];       // 16 KB
    __shared__ uint64_t sel[CAP];          // 8 KB
    __shared__ uint32_t wtot[16];
    __shared__ uint32_t s_bin, s_above, s_candv, s_cnt;

    uint64_t K[8];
#pragma unroll
    for (int j = 0; j < 8; ++j)
        K[j] = keys[b * L_ + j * 1024 + tid];

    // ---- threshold search: 12-bit digits, usually exits after level 0 ----
    uint64_t prefix = 0;
    uint32_t needed = KTOP;
    uint64_t thrlo  = 0;
    for (int level = 0; level < 4; ++level) {
        const int shift = 36 - level * 12;
        for (int i = tid; i < NBINS; i += 1024) hist[i] = 0u;
        __syncthreads();
#pragma unroll
        for (int j = 0; j < 8; ++j) {
            const bool match = (level == 0) || ((K[j] >> (shift + 12)) == prefix);
            if (match) atomicAdd(&hist[(uint32_t)(K[j] >> shift) & (NBINS - 1u)], 1u);
        }
        __syncthreads();

        // suffix scan: thread t owns bins 4t..4t+3
        const uint32_t h0 = hist[4 * tid + 0];
        const uint32_t h1 = hist[4 * tid + 1];
        const uint32_t h2 = hist[4 * tid + 2];
        const uint32_t h3 = hist[4 * tid + 3];
        const uint32_t ls = h0 + h1 + h2 + h3;
        uint32_t s = ls;
#pragma unroll
        for (int off = 1; off < 64; off <<= 1) {
            const uint32_t v = __shfl_down(s, off);
            if (lane + off < 64) s += v;
        }
        if (lane == 0) wtot[wid] = s;      // whole-wave sum
        __syncthreads();
        uint32_t after_waves = 0;
        for (int w = wid + 1; w < 16; ++w) after_waves += wtot[w];
        const uint32_t base = after_waves + (s - ls);  // sum of bins after my 4
        const uint32_t s3 = h3 + base;
        const uint32_t s2 = h2 + s3;
        const uint32_t s1 = h1 + s2;
        const uint32_t s0 = h0 + s1;
        if (s0 >= needed && s1 < needed)  { s_bin = 4u*tid+0u; s_above = s1;  s_candv = s0; }
        if (s1 >= needed && s2 < needed)  { s_bin = 4u*tid+1u; s_above = s2;  s_candv = s1; }
        if (s2 >= needed && s3 < needed)  { s_bin = 4u*tid+2u; s_above = s3;  s_candv = s2; }
        if (s3 >= needed && base < needed){ s_bin = 4u*tid+3u; s_above = base;s_candv = s3; }
        __syncthreads();

        const uint32_t T = s_bin;
        thrlo = ((prefix << 12) | T) << shift;          // conservative threshold
        const uint32_t G = s_candv + (KTOP - needed);   // global candidate count
        if (G <= CAP) break;                            // ~always at level 0
        prefix = (prefix << 12) | T;
        needed -= s_above;
        __syncthreads();
    }

    // ---- compact candidates (keys >= thrlo) ----
    if (tid == 0) s_cnt = 0u;
    __syncthreads();
#pragma unroll
    for (int j = 0; j < 8; ++j) {
        if (K[j] >= thrlo) {
            const uint32_t pos = atomicAdd(&s_cnt, 1u);
            sel[pos] = K[j];
        }
    }
    __syncthreads();
    const uint32_t nc = s_cnt;

    // ---- rank-position: r = #{candidates with larger key}; write r < KTOP ----
    if (tid < (int)nc) {
        const uint64_t mine = sel[tid];
        uint32_t r = 0;
        uint32_t i = 0;
        for (; i + 4 <= nc; i += 4) {
            r += (uint32_t)(sel[i]     > mine);
            r += (uint32_t)(sel[i + 1] > mine);
            r += (uint32_t)(sel[i + 2] > mine);
            r += (uint32_t)(sel[i + 3] > mine);
        }
        for (; i < nc; ++i) r += (uint32_t)(sel[i] > mine);
        if (r < KTOP) {
            const uint32_t idx = 8191u - (uint32_t)(mine & 0xFFFFu);
            out_ind[b * KTOP + r] = (float)idx;
            ind_i32[b * KTOP + r] = (int)idx;
        }
    }
}

// Copies the 512 selected rows per batch from reps over the zeros.
// Block = 256 threads = 8 rows (32 lanes/row, one v4f each).
__global__ __launch_bounds__(256) void copy_kernel(
        const float* __restrict__ reps, const int* __restrict__ ind_i32,
        float* __restrict__ out) {
    const int b     = blockIdx.x >> 6;          // 64 blocks per batch
    const int group = blockIdx.x & 63;
    const int r     = group * 8 + (threadIdx.x >> 5);
    const int t     = threadIdx.x & 31;
    const int idx   = ind_i32[b * KTOP + r];
    const size_t off = ((size_t)b * L_ + idx) * D_ + (size_t)t * 4;
    *(v4f*)(out + off) = *(const v4f*)(reps + off);
}

extern "C" void kernel_launch(void* const* d_in, const int* in_sizes, int n_in,
                              void* d_out, int out_size, void* d_ws, size_t ws_size,
                              hipStream_t stream) {
    const float* reps  = (const float*)d_in[0];
    const float* probs = (const float*)d_in[1];
    const float* mask  = (const float*)d_in[2];
    float* out     = (float*)d_out;
    float* out_ind = out + (size_t)B_ * L_ * D_;
    uint64_t* keys = (uint64_t*)d_ws;                    // 2 MB
    int* ind_i32   = (int*)((char*)d_ws + (size_t)B_ * L_ * 8);  // 64 KB after

    hipLaunchKernelGGL(zero_keys_kernel, dim3((B_ * L_ * D_ / 4) / 1024),
                       dim3(256), 0, stream, probs, mask, out, keys);
    hipLaunchKernelGGL(select_kernel, dim3(B_), dim3(1024), 0, stream,
                       keys, out_ind, ind_i32);
    hipLaunchKernelGGL(copy_kernel, dim3(B_ * (KTOP / 8)), dim3(256), 0, stream,
                       reps, ind_i32, out);
}